// Round 6
// baseline (250.773 us; speedup 1.0000x reference)
//
#include <hip/hip_runtime.h>
#include <hip/hip_bf16.h>
#include <stdint.h>

typedef __attribute__((ext_vector_type(8))) short bf16x8;
typedef __attribute__((ext_vector_type(4))) float f32x4;
typedef __attribute__((address_space(1))) const void g_void;
typedef __attribute__((address_space(3))) void l_void;

#define NB 16
#define NC 256
#define NHW 4096
#define NT 72      // K-steps: 9 taps x 8 ci-blocks
#define HROWS 272
#define HSTRIDE 80               // halo row bytes: 64 data + 16 pad
#define HBYTES (HROWS * HSTRIDE) // 21760
#define KSLOT 8192               // kernel tile: 128 co x 32 k x 2B

// ---------- prep: x NCHW f32 -> xt2 [b][cib][4096 pix][32 ci] bf16 ----------
__global__ __launch_bounds__(256) void prep_xt2(const float* __restrict__ x,
                                                __hip_bfloat16* __restrict__ xt2) {
  __shared__ float tile[64][65];
  const int b = blockIdx.z;
  const int cb = blockIdx.y << 6;
  const int pb = blockIdx.x << 6;
  const float* xs = x + ((size_t)(b * NC + cb) << 12) + pb;
#pragma unroll
  for (int k = 0; k < 16; ++k) {
    int idx = threadIdx.x + (k << 8);
    int c = idx >> 6, p = idx & 63;
    tile[p][c] = xs[((size_t)c << 12) + p];
  }
  __syncthreads();
#pragma unroll
  for (int k = 0; k < 16; ++k) {
    int idx = threadIdx.x + (k << 8);
    int p = idx >> 6, c = idx & 63;
    int P = pb + p, C = cb + c;
    xt2[((size_t)(b * 8 + (C >> 5)) << 17) + ((size_t)P << 5) + (C & 31)] =
        __float2bfloat16(tile[p][c]);
  }
}

// ---------- prep: kernel [b][co][ci][3][3] f32 -> kt2 [b][ct][tn][128][32] bf16 ----
// pre-swizzled: slot-chunk = data-chunk ^ ((row>>1)&3) so linear LDS copy == swizzled
__global__ __launch_bounds__(256) void prep_kt2(const float* __restrict__ kin,
                                                __hip_bfloat16* __restrict__ kt2) {
  const int bco = blockIdx.x;          // b*256 + co
  const int b = bco >> 8, co = bco & 255;
  const size_t base = (size_t)bco * 2304;
  const int ci = threadIdx.x;
  float v[9];
#pragma unroll
  for (int s = 0; s < 9; ++s) v[s] = kin[base + ci * 9 + s];
  const int cib = ci >> 5, chunk = (ci >> 3) & 3, e = ci & 7;
  const int row = co & 127, ct = co >> 7;
  const int sc = chunk ^ ((row >> 1) & 3);
#pragma unroll
  for (int s = 0; s < 9; ++s) {
    const size_t dst = (((size_t)(b * 2 + ct) * NT + (cib * 9 + s)) << 12) +
                       (row << 5) + (sc << 3) + e;
    kt2[dst] = __float2bfloat16(v[s]);
  }
}

__global__ void zero_zp(float* zp) { zp[blockIdx.x * 256 + threadIdx.x] = 0.f; }

// ---------- implicit-GEMM conv, 128x128 tile, halo-image + contiguous kernel ----
// PASS 1: A=image(M=pixel), B=kernel(N=co), out = ht2 bf16 [b][cib][pix][32] (relu)
// PASS 2: A=kernel(M=co), B=image(N=pixel), out = fp32 NCHW (x + .., relu)
template <int PASS>
__global__ __launch_bounds__(256, 2) void conv_gemm(
    const __hip_bfloat16* __restrict__ img2,  // [B][8][4096][32] (xt2 or ht2)
    const __hip_bfloat16* __restrict__ kt2,   // [B][2][72][128][32] pre-swizzled
    const float* __restrict__ xres,           // pass2 residual (NCHW f32)
    const __hip_bfloat16* __restrict__ zp,    // 8KB zeros
    void* __restrict__ outp) {
  __shared__ __align__(16) char L[2 * HBYTES + 4 * KSLOT];
  char* const Hbase = L;
  char* const Kbase = L + 2 * HBYTES;

  const int tid = threadIdx.x;
  const int lane = tid & 63;
  const int wid = tid >> 6;  // 0..3
  const int wm = wid >> 1, wn = wid & 1;

  // XCD-affine: XCD x owns logical 128-block chunk = 2 complete samples
  const int orig = blockIdx.x;
  const int g = ((orig & 7) << 7) + (orig >> 3);
  const int b = g >> 6;
  const int t = g & 63;
  const int ptile = t >> 1;  // consecutive t share ptile (image-halo reuse)
  const int ct = t & 1;
  const int pbase = ptile << 7;

  const __hip_bfloat16* imgb = img2 + ((size_t)b << 20);
  const char* ktb = (const char*)(kt2 + (((size_t)b * 2 + ct) * NT << 12));

  // fragment read offsets
  const int wI = (PASS == 1) ? wm : wn;  // image-side wave coord
  const int wK = (PASS == 1) ? wn : wm;  // kernel-side wave coord
  int ioff[4], koff[4];
#pragma unroll
  for (int f = 0; f < 4; ++f) {
    const int rr = 72 + (wI << 6) + (f << 4) + (lane & 15);
    ioff[f] = rr * HSTRIDE + ((lane >> 4) << 4);
    const int kr = (wK << 6) + (f << 4) + (lane & 15);
    koff[f] = (kr << 6) + (((lane >> 4) ^ ((kr >> 1) & 3)) << 4);
  }
  const bool killlo = (lane & 15) == 0;
  const bool killhi = (lane & 15) == 15;
  const bf16x8 z8 = {0, 0, 0, 0, 0, 0, 0, 0};

  f32x4 acc[4][4];
#pragma unroll
  for (int i = 0; i < 4; ++i)
#pragma unroll
    for (int j = 0; j < 4; ++j) acc[i][j] = (f32x4){0.f, 0.f, 0.f, 0.f};

  // kernel tile staging: 8KB contiguous, 4 waves x 2 instr x 1KB
  auto stageK = [&](int tn) {
    const int slot = tn & 3;
    const char* src = (tn < NT) ? ktb + ((size_t)tn << 13) : (const char*)zp;
#pragma unroll
    for (int i = 0; i < 2; ++i) {
      const int off = (((i << 2) + wid) << 10);
      __builtin_amdgcn_global_load_lds((g_void*)(src + off + (lane << 4)),
                                       (l_void*)(Kbase + slot * KSLOT + off), 16, 0, 0);
    }
  };

  // halo staging (register round-trip: 272 rows x 4 chunks of 16B, 80B LDS stride)
  uint4 hreg[5];
  auto haloLoad = [&](int cibn) {
    const __hip_bfloat16* hb2 = imgb + ((size_t)(cibn & 7) << 17);
#pragma unroll
    for (int q = 0; q < 5; ++q) {
      const int slot = (q << 8) + tid;  // 0..1279
      const int row = slot >> 2;
      const int ch = slot & 3;
      const int p = pbase - 72 + row;
      const bool ok = (slot < (HROWS << 2)) && ((unsigned)p < 4096u);
      const __hip_bfloat16* s = ok ? hb2 + ((size_t)p << 5) + (ch << 3) : zp;
      hreg[q] = *(const uint4*)s;
    }
  };
  auto haloWrite = [&](int hb) {
    char* hd = Hbase + hb * HBYTES;
#pragma unroll
    for (int q = 0; q < 5; ++q) {
      const int slot = (q << 8) + tid;
      const int row = slot >> 2;
      const int ch = slot & 3;
      if (slot < (HROWS << 2)) *(uint4*)(hd + row * HSTRIDE + (ch << 4)) = hreg[q];
    }
  };

  // prologue: halo(cib=0) + 3 kernel tiles in flight
  // issue order: H x5, K0 x2, K1 x2, K2 x2  (11 outstanding)
  haloLoad(0);
  stageK(0);
  stageK(1);
  stageK(2);
  asm volatile("s_waitcnt vmcnt(6)" ::: "memory");  // drain H x5; K0..K2 in flight
  haloWrite(0);
  asm volatile("s_waitcnt lgkmcnt(0)" ::: "memory");

#pragma unroll 1
  for (int cib = 0; cib < 8; ++cib) {
    const char* Hc = Hbase + (cib & 1) * HBYTES;
#pragma unroll
    for (int s = 0; s < 9; ++s) {
      const int kk = cib * 9 + s;
      // top-of-step wait: guarantee tile kk resident (vmcnt retires in ISSUE order;
      // halo x5 issued at s==3 bottom sit OLDER than K tiles staged s=4..7 tops):
      //  s<=3: out = K(kk),K(+1),K(+2)            -> vmcnt(4) drains K(kk)
      //  s=4..6: out = K..,H5,K..  (11 total)     -> vmcnt(9) drains K(kk)
      //  s==7: out = H5,K(kk),K(+1),K(+2)         -> vmcnt(4) drains H5+K(kk)
      //  s==8: out = K(kk),K(+1),K(+2)            -> vmcnt(4)
      if (s >= 4 && s <= 6)
        asm volatile("s_waitcnt vmcnt(9)" ::: "memory");
      else
        asm volatile("s_waitcnt vmcnt(4)" ::: "memory");
      __builtin_amdgcn_s_barrier();
      stageK(kk + 3);

      const char* Kt = Kbase + (kk & 3) * KSLOT;
      const int dh = s / 3 - 1, dw = s % 3 - 1;  // compile-time (s unrolled)
      const int tapoff = (dh * 64 + dw) * HSTRIDE;
      bf16x8 fi[4], fk[4];
#pragma unroll
      for (int f = 0; f < 4; ++f) fi[f] = *(const bf16x8*)(Hc + ioff[f] + tapoff);
#pragma unroll
      for (int f = 0; f < 4; ++f) fk[f] = *(const bf16x8*)(Kt + koff[f]);
      // w-edge wrap masking (one compile-time lane per edge fragment)
      if (dw == 1) fi[3] = killhi ? z8 : fi[3];
      if (dw == -1) fi[0] = killlo ? z8 : fi[0];

      asm volatile("s_waitcnt lgkmcnt(0)" ::: "memory");
      __builtin_amdgcn_sched_barrier(0);
      __builtin_amdgcn_s_setprio(1);
#pragma unroll
      for (int i = 0; i < 4; ++i)
#pragma unroll
        for (int j = 0; j < 4; ++j) {
          if (PASS == 1)
            acc[i][j] = __builtin_amdgcn_mfma_f32_16x16x32_bf16(fi[i], fk[j], acc[i][j], 0, 0, 0);
          else
            acc[i][j] = __builtin_amdgcn_mfma_f32_16x16x32_bf16(fk[i], fi[j], acc[i][j], 0, 0, 0);
        }
      __builtin_amdgcn_s_setprio(0);

      if (s == 3) haloLoad(cib + 1);  // issue-early (T14); write-late at s==7
      if (s == 7) {
        // hregs were drained by this step's top vmcnt(4); just write + fence
        haloWrite((cib & 1) ^ 1);
        asm volatile("s_waitcnt lgkmcnt(0)" ::: "memory");
      }
    }
  }
  // drain tail dummy LDS-DMA before epilogue/endpgm (else late DMA can corrupt
  // a successor block's LDS)
  asm volatile("s_waitcnt vmcnt(0)" ::: "memory");
  __builtin_amdgcn_sched_barrier(0);

  const int lg = lane >> 4;
  const int ln = lane & 15;
  if (PASS == 1) {
    __hip_bfloat16* ho = (__hip_bfloat16*)outp;  // ht2 layout [b][cib][pix][32]
#pragma unroll
    for (int i = 0; i < 4; ++i)
#pragma unroll
      for (int j = 0; j < 4; ++j)
#pragma unroll
        for (int r = 0; r < 4; ++r) {
          int pixel = pbase + (wm << 6) + (i << 4) + (lg << 2) + r;
          int co = (ct << 7) + (wn << 6) + (j << 4) + ln;
          float v = acc[i][j][r];
          v = v > 0.f ? v : 0.f;
          ho[((size_t)(b * 8 + (co >> 5)) << 17) + ((size_t)pixel << 5) + (co & 31)] =
              __float2bfloat16(v);
        }
  } else {
    float* oo = (float*)outp;
#pragma unroll
    for (int i = 0; i < 4; ++i)
#pragma unroll
      for (int j = 0; j < 4; ++j)
#pragma unroll
        for (int r = 0; r < 4; ++r) {
          int co = (ct << 7) + (wm << 6) + (i << 4) + (lg << 2) + r;
          int pixel = pbase + (wn << 6) + (j << 4) + ln;
          size_t idx = ((size_t)(b * NC + co) << 12) + pixel;
          float v = acc[i][j][r] + xres[idx];
          oo[idx] = v > 0.f ? v : 0.f;
        }
  }
}

extern "C" void kernel_launch(void* const* d_in, const int* in_sizes, int n_in,
                              void* d_out, int out_size, void* d_ws, size_t ws_size,
                              hipStream_t stream) {
  const float* x = (const float*)d_in[0];
  const float* k1 = (const float*)d_in[1];
  const float* k2 = (const float*)d_in[2];

  // ws: xt2 (33.6MB) | ht2 (33.6MB) | kt2 (18.9MB, reused k1 then k2) | zp (8KB)
  __hip_bfloat16* xt2 = (__hip_bfloat16*)d_ws;
  __hip_bfloat16* ht2 = xt2 + (size_t)NB * 8 * NHW * 32;
  __hip_bfloat16* kt2 = ht2 + (size_t)NB * 8 * NHW * 32;
  float* zp = (float*)(kt2 + (size_t)NB * 2 * NT * 128 * 32);

  zero_zp<<<dim3(8), 256, 0, stream>>>(zp);
  prep_xt2<<<dim3(64, 4, NB), 256, 0, stream>>>(x, xt2);
  prep_kt2<<<dim3(NB * NC), 256, 0, stream>>>(k1, kt2);
  conv_gemm<1><<<dim3(1024), 256, 0, stream>>>(xt2, kt2, nullptr,
                                               (const __hip_bfloat16*)zp, (void*)ht2);
  prep_kt2<<<dim3(NB * NC), 256, 0, stream>>>(k2, kt2);
  conv_gemm<2><<<dim3(1024), 256, 0, stream>>>(ht2, kt2, x,
                                               (const __hip_bfloat16*)zp, d_out);
}

// Round 7
// 191.820 us; speedup vs baseline: 1.3073x; 1.3073x over previous
//
#include <hip/hip_runtime.h>
#include <hip/hip_bf16.h>
#include <stdint.h>

typedef __attribute__((ext_vector_type(8))) short bf16x8;
typedef __attribute__((ext_vector_type(4))) float f32x4;
typedef __attribute__((address_space(1))) const void g_void;
typedef __attribute__((address_space(3))) void l_void;

#define NB 16
#define NC 256
#define NHW 4096
#define NT 72      // K-steps: 9 taps x 8 ci-blocks
#define ASLOT 8192
#define KSLOT 8192
#define SLOTB (ASLOT + KSLOT)  // 16KB per pipeline slot, 3 slots = 48KB

// ---------- prep: x NCHW f32 -> xt2 [b][cib][4096 pix][32 ci] bf16 ----------
__global__ __launch_bounds__(256) void prep_xt2(const float* __restrict__ x,
                                                __hip_bfloat16* __restrict__ xt2) {
  __shared__ float tile[64][65];
  const int b = blockIdx.z;
  const int cb = blockIdx.y << 6;
  const int pb = blockIdx.x << 6;
  const float* xs = x + ((size_t)(b * NC + cb) << 12) + pb;
#pragma unroll
  for (int k = 0; k < 16; ++k) {
    int idx = threadIdx.x + (k << 8);
    int c = idx >> 6, p = idx & 63;
    tile[p][c] = xs[((size_t)c << 12) + p];
  }
  __syncthreads();
#pragma unroll
  for (int k = 0; k < 16; ++k) {
    int idx = threadIdx.x + (k << 8);
    int p = idx >> 6, c = idx & 63;
    int P = pb + p, C = cb + c;
    xt2[((size_t)(b * 8 + (C >> 5)) << 17) + ((size_t)P << 5) + (C & 31)] =
        __float2bfloat16(tile[p][c]);
  }
}

// ---------- prep: kernel [b][co][ci][3][3] f32 -> kt2 [b][ct][tn][128][32] bf16 ----
// tn = cib*9+s; pre-swizzled so linear LDS copy == swizzled layout
__global__ __launch_bounds__(256) void prep_kt2(const float* __restrict__ kin,
                                                __hip_bfloat16* __restrict__ kt2) {
  const int bco = blockIdx.x;  // b*256 + co
  const int b = bco >> 8, co = bco & 255;
  const size_t base = (size_t)bco * 2304;
  const int ci = threadIdx.x;
  float v[9];
#pragma unroll
  for (int s = 0; s < 9; ++s) v[s] = kin[base + ci * 9 + s];
  const int cib = ci >> 5, chunk = (ci >> 3) & 3, e = ci & 7;
  const int row = co & 127, ct = co >> 7;
  const int sc = chunk ^ ((row >> 1) & 3);
#pragma unroll
  for (int s = 0; s < 9; ++s) {
    const size_t dst = (((size_t)(b * 2 + ct) * NT + (cib * 9 + s)) << 12) +
                       (row << 5) + (sc << 3) + e;
    kt2[dst] = __float2bfloat16(v[s]);
  }
}

__global__ void zero_zp(float* zp) { zp[blockIdx.x * 256 + threadIdx.x] = 0.f; }

// ---------- implicit-GEMM conv, 128x128 tile, 3-slot pipeline, 3 blocks/CU ----
// PASS 1: A=image(M=pixel), B=kernel(N=co), out = ht2 bf16 [b][cib][pix][32] (relu)
// PASS 2: A=kernel(M=co), B=image(N=pixel), out = fp32 NCHW (x + .., relu)
template <int PASS>
__global__ __launch_bounds__(256, 3) void conv_gemm(
    const __hip_bfloat16* __restrict__ img2,  // [B][8][4096][32] (xt2 or ht2)
    const __hip_bfloat16* __restrict__ kt2,   // [B][2][72][128][32] pre-swizzled
    const float* __restrict__ xres,           // pass2 residual (NCHW f32)
    const __hip_bfloat16* __restrict__ zp,    // 8KB zeros
    void* __restrict__ outp) {
  __shared__ __align__(16) char L[3 * SLOTB];  // [slot][A 8KB | K 8KB]

  const int tid = threadIdx.x;
  const int lane = tid & 63;
  const int wid = tid >> 6;  // 0..3
  const int wm = wid >> 1, wn = wid & 1;

  // XCD-affine: XCD x owns logical 128-block chunk = 2 complete samples
  const int orig = blockIdx.x;
  const int g = ((orig & 7) << 7) + (orig >> 3);
  const int b = g >> 6;
  const int t = g & 63;
  const int ptile = t >> 1;
  const int ct = t & 1;
  const int pbase = ptile << 7;

  const char* xb = (const char*)img2 + ((size_t)b << 21);  // sample base (bytes)
  const char* ktb = (const char*)kt2 + (((size_t)(b * 2 + ct) * NT) << 13);
  const char* zpb = (const char*)zp;

  // staging lane geometry: instr covers 16 rows; lane -> row +(lane>>2),
  // HW LDS slot lane&3; source chunk pre-swizzled: sch = (lane&3) ^ ((srow>>1)&3)
  const int srow = lane >> 2;
  const int sch = (lane & 3) ^ ((srow >> 1) & 3);

  // fragment read offsets (bytes)
  const int wI = (PASS == 1) ? wm : wn;  // image-side wave coord
  const int wK = (PASS == 1) ? wn : wm;  // kernel-side wave coord
  int ioff[4], koff[4];
#pragma unroll
  for (int f = 0; f < 4; ++f) {
    const int ir = (wI << 6) + (f << 4) + (lane & 15);
    ioff[f] = (ir << 6) + ((((lane >> 4) ^ ((ir >> 1) & 3))) << 4);
    const int kr = (wK << 6) + (f << 4) + (lane & 15);
    koff[f] = (kr << 6) + ((((lane >> 4) ^ ((kr >> 1) & 3))) << 4);
  }
  const bool killlo = (lane & 15) == 0;
  const bool killhi = (lane & 15) == 15;
  const bf16x8 z8 = {0, 0, 0, 0, 0, 0, 0, 0};

  f32x4 acc[4][4];
#pragma unroll
  for (int i = 0; i < 4; ++i)
#pragma unroll
    for (int j = 0; j < 4; ++j) acc[i][j] = (f32x4){0.f, 0.f, 0.f, 0.f};

  // A-tile stage: one contiguous 8KB block at tap offset (dh*64+dw)*64B.
  // h-OOB groups (only ptile 0/31) -> zp; w-edge wrap killed at fragment read.
  auto stageA = [&](int slot, int cibp, int dh, int dw, bool dummy) {
    const char* cb = xb + ((size_t)(cibp & 7) << 18);
#pragma unroll
    for (int i = 0; i < 2; ++i) {
      const int grp = (i << 2) + wid;
      const int h = (ptile << 1) + (grp >> 2) + dh;  // uniform per instr
      const bool ok = !dummy && ((unsigned)h < 64u);
      const int off = ((pbase + (grp << 4) + srow + (dh << 6) + dw) << 6) + (sch << 4);
      const char* src = ok ? cb + off : zpb + (lane << 4);
      __builtin_amdgcn_global_load_lds((g_void*)src,
                                       (l_void*)(L + slot * SLOTB + (grp << 10)), 16, 0, 0);
    }
  };
  auto stageK = [&](int slot, int tn) {
    const char* src0 = ktb + ((size_t)tn << 13);
#pragma unroll
    for (int i = 0; i < 2; ++i) {
      const int grp = (i << 2) + wid;
      const char* src = (tn < NT) ? src0 + (grp << 10) + (lane << 4) : zpb + (lane << 4);
      __builtin_amdgcn_global_load_lds(
          (g_void*)src, (l_void*)(L + slot * SLOTB + ASLOT + (grp << 10)), 16, 0, 0);
    }
  };

  // prologue: steps 0 (tap -1,-1) and 1 (tap -1,0) in flight (8 loads/wave)
  stageA(0, 0, -1, -1, false);
  stageK(0, 0);
  stageA(1, 0, -1, 0, false);
  stageK(1, 1);

#pragma unroll 1
  for (int cib = 0; cib < 8; ++cib) {
#pragma unroll
    for (int s = 0; s < 9; ++s) {  // s compile-time (unrolled)
      const int kk = cib * 9 + s;
      // drain tile kk (4 oldest); kk+1 stays in flight
      asm volatile("s_waitcnt vmcnt(4)" ::: "memory");
      __builtin_amdgcn_s_barrier();
      // stage step kk+2 into slot (kk+2)%3 (its last readers passed this barrier)
      {
        const int s2 = (s + 2) % 9;          // compile-time
        const int cib2 = cib + (s + 2) / 9;  // uniform runtime
        const int tn = kk + 2;
        stageA(tn % 3, cib2, s2 / 3 - 1, s2 % 3 - 1, tn >= NT);
        stageK(tn % 3, tn);
      }

      const char* As = L + (kk % 3) * SLOTB;
      const char* Ks = As + ASLOT;
      bf16x8 fi[4], fk[4];
#pragma unroll
      for (int f = 0; f < 4; ++f) fi[f] = *(const bf16x8*)(As + ioff[f]);
#pragma unroll
      for (int f = 0; f < 4; ++f) fk[f] = *(const bf16x8*)(Ks + koff[f]);
      // w-edge wrap masking (compile-time tap)
      const int dw = s % 3 - 1;
      if (dw == 1) fi[3] = killhi ? z8 : fi[3];
      if (dw == -1) fi[0] = killlo ? z8 : fi[0];

#pragma unroll
      for (int i = 0; i < 4; ++i)
#pragma unroll
        for (int j = 0; j < 4; ++j) {
          if (PASS == 1)
            acc[i][j] = __builtin_amdgcn_mfma_f32_16x16x32_bf16(fi[i], fk[j], acc[i][j], 0, 0, 0);
          else
            acc[i][j] = __builtin_amdgcn_mfma_f32_16x16x32_bf16(fk[i], fi[j], acc[i][j], 0, 0, 0);
        }
    }
  }
  // drain tail dummy LDS-DMA before epilogue/endpgm
  asm volatile("s_waitcnt vmcnt(0)" ::: "memory");
  __builtin_amdgcn_sched_barrier(0);

  const int lg = lane >> 4;
  const int ln = lane & 15;
  if (PASS == 1) {
    __hip_bfloat16* ho = (__hip_bfloat16*)outp;  // ht2 layout [b][cib][pix][32]
#pragma unroll
    for (int i = 0; i < 4; ++i)
#pragma unroll
      for (int j = 0; j < 4; ++j)
#pragma unroll
        for (int r = 0; r < 4; ++r) {
          int pixel = pbase + (wm << 6) + (i << 4) + (lg << 2) + r;
          int co = (ct << 7) + (wn << 6) + (j << 4) + ln;
          float v = acc[i][j][r];
          v = v > 0.f ? v : 0.f;
          ho[((size_t)(b * 8 + (co >> 5)) << 17) + ((size_t)pixel << 5) + (co & 31)] =
              __float2bfloat16(v);
        }
  } else {
    float* oo = (float*)outp;
#pragma unroll
    for (int i = 0; i < 4; ++i)
#pragma unroll
      for (int j = 0; j < 4; ++j)
#pragma unroll
        for (int r = 0; r < 4; ++r) {
          int co = (ct << 7) + (wm << 6) + (i << 4) + (lg << 2) + r;
          int pixel = pbase + (wn << 6) + (j << 4) + ln;
          size_t idx = ((size_t)(b * NC + co) << 12) + pixel;
          float v = acc[i][j][r] + xres[idx];
          oo[idx] = v > 0.f ? v : 0.f;
        }
  }
}

extern "C" void kernel_launch(void* const* d_in, const int* in_sizes, int n_in,
                              void* d_out, int out_size, void* d_ws, size_t ws_size,
                              hipStream_t stream) {
  const float* x = (const float*)d_in[0];
  const float* k1 = (const float*)d_in[1];
  const float* k2 = (const float*)d_in[2];

  // ws: pad 256B | xt2 (33.6MB) | ht2 (33.6MB) | kt2 (18.9MB) | zp (8KB)
  // (pad so the pixel=-1 speculative read before xt2 stays in mapped memory)
  char* w = (char*)d_ws;
  __hip_bfloat16* xt2 = (__hip_bfloat16*)(w + 256);
  __hip_bfloat16* ht2 = xt2 + (size_t)NB * 8 * NHW * 32;
  __hip_bfloat16* kt2 = ht2 + (size_t)NB * 8 * NHW * 32;
  float* zp = (float*)(kt2 + (size_t)NB * 2 * NT * 128 * 32);

  zero_zp<<<dim3(8), 256, 0, stream>>>(zp);
  prep_xt2<<<dim3(64, 4, NB), 256, 0, stream>>>(x, xt2);
  prep_kt2<<<dim3(NB * NC), 256, 0, stream>>>(k1, kt2);
  conv_gemm<1><<<dim3(1024), 256, 0, stream>>>(xt2, kt2, nullptr,
                                               (const __hip_bfloat16*)zp, (void*)ht2);
  prep_kt2<<<dim3(NB * NC), 256, 0, stream>>>(k2, kt2);
  conv_gemm<2><<<dim3(1024), 256, 0, stream>>>(ht2, kt2, x,
                                               (const __hip_bfloat16*)zp, d_out);
}